// Round 1
// baseline (627.286 us; speedup 1.0000x reference)
//
#include <hip/hip_runtime.h>
#include <math.h>

// Conv-KNRM: B=128, QLEN=30, DLEN=256, EMB=300, C=128, K=11 kernels, 3 grams.
//
// Pipeline (all fp32, round-1 correctness-first):
//   K0 transpose_w : w[g][c][e][j] -> wt[g][j][e][c]  (coalesced conv staging)
//   K1 conv_kernel : conv+bias+relu+L2-normalize, out channel-major [g][b][c][l]
//   K2 pool_kernel : per (pair,b): cos over c=128, RBF x11, sum over d -> pkq
//   K3 final_kernel: log/clip/qmask/sum_q, dot with dense_w -> out[b]
//
// ws layout (floats):
//   wt   @ 0          : 230400   (6*300*128)
//   qnT  @ 230400     : 1474560  (3*128*128*30)
//   dnT  @ 1704960    : 12582912 (3*128*128*256)
//   pkq  @ 14287872   : 380160   (9*128*30*11)
//   total 14668032 floats = 58.7 MB

#define B_SZ 128
#define EMB 300
#define COUT 128

__global__ __launch_bounds__(256) void transpose_w(
    const float* __restrict__ w1, const float* __restrict__ w2,
    const float* __restrict__ w3, float* __restrict__ wt) {
  int idx = blockIdx.x * 256 + threadIdx.x;
  if (idx >= 230400) return;
  const float* w; int k; int o;
  if (idx < 38400)       { w = w1; k = 1; o = idx; }
  else if (idx < 115200) { w = w2; k = 2; o = idx - 38400; }
  else                   { w = w3; k = 3; o = idx - 115200; }
  int c = o & 127;
  int e = (o >> 7) % 300;
  int j = (o >> 7) / 300;
  wt[idx] = w[(c * 300 + e) * k + j];
}

// One block: 32 l-rows x 128 channels for one (gram, batch, l-tile).
// Thread: 4 rows x 4 channels register block.
__global__ __launch_bounds__(256) void conv_kernel(
    const float* __restrict__ x, int L,
    const float* __restrict__ wt,
    const float* __restrict__ b1, const float* __restrict__ b2,
    const float* __restrict__ b3,
    float* __restrict__ outT) {
  const int g = blockIdx.z;
  const int k = g + 1;
  const float* wtg  = wt + (g == 0 ? 0 : (g == 1 ? 38400 : 115200));
  const float* bias = (g == 0 ? b1 : (g == 1 ? b2 : b3));
  const int b  = blockIdx.y;
  const int l0 = blockIdx.x * 32;
  const int t  = threadIdx.x;
  const int tc = t & 31, tr = t >> 5;
  const int c0 = tc * 4, r0 = tr * 4;

  __shared__ float xs[32][37];    // [e][row], pad 37 (odd) -> conflict-free
  __shared__ float wsm[32][132];  // [e][c],  pad 132 keeps float4 alignment

  float acc[4][4] = {};
  const float* xb = x + (size_t)b * L * EMB;

  for (int ec = 0; ec < EMB; ec += 32) {
    const int EC = (EMB - ec < 32) ? (EMB - ec) : 32;
    __syncthreads();  // prior xs readers done
    for (int idx = t; idx < EC * 34; idx += 256) {
      int e = idx % EC, row = idx / EC;
      int l = l0 + row;
      xs[e][row] = (l < L) ? xb[l * EMB + ec + e] : 0.0f;
    }
    for (int j = 0; j < k; ++j) {
      __syncthreads();  // xs ready / prior wsm readers done
      for (int idx = t; idx < EC * 128; idx += 256) {
        int c = idx & 127, e = idx >> 7;
        wsm[e][c] = wtg[(j * 300 + ec + e) * 128 + c];
      }
      __syncthreads();
      #pragma unroll 4
      for (int e = 0; e < EC; ++e) {
        float a0 = xs[e][r0 + j + 0];
        float a1 = xs[e][r0 + j + 1];
        float a2 = xs[e][r0 + j + 2];
        float a3 = xs[e][r0 + j + 3];
        const float4 bv = *reinterpret_cast<const float4*>(&wsm[e][c0]);
        acc[0][0] += a0 * bv.x; acc[0][1] += a0 * bv.y;
        acc[0][2] += a0 * bv.z; acc[0][3] += a0 * bv.w;
        acc[1][0] += a1 * bv.x; acc[1][1] += a1 * bv.y;
        acc[1][2] += a1 * bv.z; acc[1][3] += a1 * bv.w;
        acc[2][0] += a2 * bv.x; acc[2][1] += a2 * bv.y;
        acc[2][2] += a2 * bv.z; acc[2][3] += a2 * bv.w;
        acc[3][0] += a3 * bv.x; acc[3][1] += a3 * bv.y;
        acc[3][2] += a3 * bv.z; acc[3][3] += a3 * bv.w;
      }
    }
  }

  float bia[4];
  #pragma unroll
  for (int ci = 0; ci < 4; ++ci) bia[ci] = bias[c0 + ci];

  float* ob = outT + (size_t)(g * B_SZ + b) * COUT * L;  // [c][l]
  #pragma unroll
  for (int ri = 0; ri < 4; ++ri) {
    float y[4]; float s = 0.0f;
    #pragma unroll
    for (int ci = 0; ci < 4; ++ci) {
      float v = acc[ri][ci] + bia[ci];
      v = fmaxf(v, 0.0f);
      y[ci] = v;
      s += v * v;
    }
    // reduce sum of squares over the 32 channel-threads (same tr group)
    s += __shfl_xor(s, 1);
    s += __shfl_xor(s, 2);
    s += __shfl_xor(s, 4);
    s += __shfl_xor(s, 8);
    s += __shfl_xor(s, 16);
    float inv = 1.0f / (sqrtf(s) + 1e-13f);
    int l = l0 + r0 + ri;
    if (l < L) {
      #pragma unroll
      for (int ci = 0; ci < 4; ++ci) ob[(c0 + ci) * L + l] = y[ci] * inv;
    }
  }
}

// One block per (pair, b). 128 threads = 16 d-threads x 8 q-threads,
// each 4q x 4d register tile; doc dim processed in 4 chunks of 64.
__global__ __launch_bounds__(128) void pool_kernel(
    const float* __restrict__ qnT, const float* __restrict__ dnT,
    const float* __restrict__ qmask, const float* __restrict__ dmask,
    float* __restrict__ pkq) {
  const float MU[11] = {1.0f, 0.9f, 0.7f, 0.5f, 0.3f, 0.1f,
                        -0.1f, -0.3f, -0.5f, -0.7f, -0.9f};
  const float INV2S2[11] = {500000.0f, 50.0f, 50.0f, 50.0f, 50.0f, 50.0f,
                            50.0f, 50.0f, 50.0f, 50.0f, 50.0f};
  const int pair = blockIdx.x;  // pair = i*3 + t
  const int b    = blockIdx.y;
  const int ig   = pair / 3;
  const int tg   = pair % 3;
  const float* qslab = qnT + (size_t)(ig * B_SZ + b) * COUT * 30;   // [c][30]
  const float* dslab = dnT + (size_t)(tg * B_SZ + b) * COUT * 256;  // [c][256]

  __shared__ float qs[128][36];
  __shared__ float ds[128][64];

  const int t  = threadIdx.x;
  const int dt = t & 15, qt = t >> 4;
  const int q0 = qt * 4, d0 = dt * 4;

  for (int idx = t; idx < 128 * 32; idx += 128) {
    int c = idx >> 5, q = idx & 31;
    qs[c][q] = (q < 30) ? qslab[c * 30 + q] : 0.0f;
  }

  float qm[4];
  #pragma unroll
  for (int qi = 0; qi < 4; ++qi) {
    int q = q0 + qi;
    qm[qi] = (q < 30) ? qmask[b * 30 + q] : 0.0f;
  }

  float feat[4][11];
  #pragma unroll
  for (int qi = 0; qi < 4; ++qi)
    #pragma unroll
    for (int kk = 0; kk < 11; ++kk) feat[qi][kk] = 0.0f;

  for (int ch = 0; ch < 4; ++ch) {
    __syncthreads();  // qs ready (ch=0) / prior ds readers done
    for (int idx = t; idx < 128 * 64; idx += 128) {
      int c = idx >> 6, d = idx & 63;
      ds[c][d] = dslab[c * 256 + ch * 64 + d];
    }
    __syncthreads();

    float acc[4][4] = {};
    #pragma unroll 8
    for (int c = 0; c < 128; ++c) {
      const float4 qv = *reinterpret_cast<const float4*>(&qs[c][q0]);
      const float4 dv = *reinterpret_cast<const float4*>(&ds[c][d0]);
      acc[0][0] += qv.x * dv.x; acc[0][1] += qv.x * dv.y;
      acc[0][2] += qv.x * dv.z; acc[0][3] += qv.x * dv.w;
      acc[1][0] += qv.y * dv.x; acc[1][1] += qv.y * dv.y;
      acc[1][2] += qv.y * dv.z; acc[1][3] += qv.y * dv.w;
      acc[2][0] += qv.z * dv.x; acc[2][1] += qv.z * dv.y;
      acc[2][2] += qv.z * dv.z; acc[2][3] += qv.z * dv.w;
      acc[3][0] += qv.w * dv.x; acc[3][1] += qv.w * dv.y;
      acc[3][2] += qv.w * dv.z; acc[3][3] += qv.w * dv.w;
    }

    float dm[4];
    #pragma unroll
    for (int di = 0; di < 4; ++di) dm[di] = dmask[b * 256 + ch * 64 + d0 + di];

    #pragma unroll
    for (int qi = 0; qi < 4; ++qi) {
      #pragma unroll
      for (int di = 0; di < 4; ++di) {
        float m  = qm[qi] * dm[di];
        float cm = acc[qi][di] * m;
        #pragma unroll
        for (int kk = 0; kk < 11; ++kk) {
          float d2 = cm - MU[kk];
          feat[qi][kk] += __expf(-d2 * d2 * INV2S2[kk]) * m;
        }
      }
    }
  }

  // reduce feat over the 16 d-threads (consecutive lanes within qt group)
  #pragma unroll
  for (int qi = 0; qi < 4; ++qi) {
    #pragma unroll
    for (int kk = 0; kk < 11; ++kk) {
      float v = feat[qi][kk];
      v += __shfl_xor(v, 1);
      v += __shfl_xor(v, 2);
      v += __shfl_xor(v, 4);
      v += __shfl_xor(v, 8);
      feat[qi][kk] = v;
    }
  }
  if (dt == 0) {
    #pragma unroll
    for (int qi = 0; qi < 4; ++qi) {
      int q = q0 + qi;
      if (q < 30) {
        float* p = pkq + ((size_t)(pair * B_SZ + b) * 30 + q) * 11;
        #pragma unroll
        for (int kk = 0; kk < 11; ++kk) p[kk] = feat[qi][kk];
      }
    }
  }
}

__global__ __launch_bounds__(128) void final_kernel(
    const float* __restrict__ pkq, const float* __restrict__ qmask,
    const float* __restrict__ dw, float* __restrict__ out) {
  const int b = blockIdx.x;
  const int t = threadIdx.x;
  float s = 0.0f;
  for (int idx = t; idx < 9 * 30 * 11; idx += 128) {
    int pair = idx / 330;
    int rem  = idx % 330;
    int q    = rem / 11;
    int kk   = rem % 11;
    float v = pkq[((size_t)(pair * B_SZ + b) * 30 + q) * 11 + kk];
    s += __logf(fmaxf(v, 1e-10f)) * 0.01f * qmask[b * 30 + q] * dw[pair * 11 + kk];
  }
  s += __shfl_xor(s, 1);  s += __shfl_xor(s, 2);  s += __shfl_xor(s, 4);
  s += __shfl_xor(s, 8);  s += __shfl_xor(s, 16); s += __shfl_xor(s, 32);
  __shared__ float part[2];
  if ((t & 63) == 0) part[t >> 6] = s;
  __syncthreads();
  if (t == 0) out[b] = part[0] + part[1];
}

extern "C" void kernel_launch(void* const* d_in, const int* in_sizes, int n_in,
                              void* d_out, int out_size, void* d_ws, size_t ws_size,
                              hipStream_t stream) {
  const float* qemb  = (const float*)d_in[0];
  const float* demb  = (const float*)d_in[1];
  const float* qmask = (const float*)d_in[2];
  const float* dmask = (const float*)d_in[3];
  const float* w1 = (const float*)d_in[4];
  const float* b1 = (const float*)d_in[5];
  const float* w2 = (const float*)d_in[6];
  const float* b2 = (const float*)d_in[7];
  const float* w3 = (const float*)d_in[8];
  const float* b3 = (const float*)d_in[9];
  const float* dw = (const float*)d_in[10];

  float* ws  = (float*)d_ws;
  float* wt  = ws;
  float* qnT = ws + 230400;
  float* dnT = qnT + 1474560;
  float* pkq = dnT + 12582912;

  transpose_w<<<900, 256, 0, stream>>>(w1, w2, w3, wt);
  conv_kernel<<<dim3(1, B_SZ, 3), 256, 0, stream>>>(qemb, 30, wt, b1, b2, b3, qnT);
  conv_kernel<<<dim3(8, B_SZ, 3), 256, 0, stream>>>(demb, 256, wt, b1, b2, b3, dnT);
  pool_kernel<<<dim3(9, B_SZ), 128, 0, stream>>>(qnT, dnT, qmask, dmask, pkq);
  final_kernel<<<B_SZ, 128, 0, stream>>>(pkq, qmask, dw, (float*)d_out);
}

// Round 2
// 298.779 us; speedup vs baseline: 2.0995x; 2.0995x over previous
//
#include <hip/hip_runtime.h>
#include <math.h>

// Conv-KNRM on MI355X. B=128, QLEN=30, DLEN=256, EMB=300 (pad 320), C=128.
//
// Pipeline:
//   prep_w      : w fp32 [C,E,k] -> wt bf16 [plane(g,j)][c][320] (e zero-pad)
//   conv_mfma   : bf16 MFMA conv + bias + relu + L2-norm -> bf16 [g][b][l][c]
//   pool_kernel : cos over c=128 (fp32 VALU), RBF x11, sum over d -> pkq
//   final_kernel: log/clip/qmask/sum_q dot dense_w -> out[128]
//
// ws layout: wt bf16 245760 | qn bf16 1474560 | dn bf16 12582912 | pkq f32 380160

typedef __bf16 bf16x8 __attribute__((ext_vector_type(8)));
typedef float f32x4 __attribute__((ext_vector_type(4)));

static __device__ __forceinline__ unsigned short f2bf(float f) {
  union { float f; unsigned int u; } v; v.f = f;
  unsigned int r = v.u + 0x7FFFu + ((v.u >> 16) & 1u);  // RNE
  return (unsigned short)(r >> 16);
}
static __device__ __forceinline__ float bf2f(unsigned short h) {
  union { unsigned int u; float f; } v; v.u = ((unsigned int)h) << 16;
  return v.f;
}

__global__ __launch_bounds__(256) void prep_w(
    const float* __restrict__ w1, const float* __restrict__ w2,
    const float* __restrict__ w3, unsigned short* __restrict__ wt) {
  int idx = blockIdx.x * 256 + threadIdx.x;
  if (idx >= 245760) return;  // 6 planes * 128 c * 320 e
  int e = idx % 320;
  int c = (idx / 320) & 127;
  int p = idx / 40960;
  const float* w; int k, j;
  if (p == 0)      { w = w1; k = 1; j = 0; }
  else if (p <= 2) { w = w2; k = 2; j = p - 1; }
  else             { w = w3; k = 3; j = p - 3; }
  float v = (e < 300) ? w[(c * 300 + e) * k + j] : 0.0f;
  wt[idx] = f2bf(v);
}

// Block: 128 l x 128 c tile for one (gram, batch). 256 thr = 4 waves, each
// 64x64 via 4x4 MFMA 16x16x32 frags. KC=32 e-chunk; A staged with +2 shift
// rows so all j taps reuse one LDS image. LDS strides 40 bf16 (80 B): 2-way.
__global__ __launch_bounds__(256) void conv_mfma(
    const float* __restrict__ x, int L,
    const unsigned short* __restrict__ wt,
    const float* __restrict__ b1, const float* __restrict__ b2,
    const float* __restrict__ b3,
    unsigned short* __restrict__ outT) {
  const int g = blockIdx.z;
  const int k = g + 1;
  const int pstart = (g * (g + 1)) >> 1;  // plane base for this gram
  const float* bias = (g == 0 ? b1 : (g == 1 ? b2 : b3));
  const int b  = blockIdx.y;
  const int l0 = blockIdx.x * 128;

  __shared__ unsigned short As[130][40];      // [row][e32], pad 40
  __shared__ unsigned short Bs[3][128][40];   // [j][c][e32]
  __shared__ float ssq[128];

  const int t = threadIdx.x;
  const int wv = t >> 6, lane = t & 63;
  const int wm = wv >> 1, wn = wv & 1;
  const int m0 = wm * 64, n0 = wn * 64;
  const int quad = lane >> 4, lrow = lane & 15;

  if (t < 128) ssq[t] = 0.0f;

  f32x4 acc[4][4];
  #pragma unroll
  for (int i = 0; i < 4; ++i)
    #pragma unroll
    for (int jj = 0; jj < 4; ++jj) acc[i][jj] = (f32x4){0.f, 0.f, 0.f, 0.f};

  const float* xb = x + (size_t)b * L * 300;

  for (int ec = 0; ec < 320; ec += 32) {
    __syncthreads();  // prior readers done (also publishes ssq=0 first iter)
    // stage A: 130 rows x 32 e (fp32 -> bf16)
    for (int idx = t; idx < 130 * 8; idx += 256) {
      int r = idx >> 3, e4 = idx & 7;
      int e = ec + e4 * 4;
      int l = l0 + r;
      float4 v = make_float4(0.f, 0.f, 0.f, 0.f);
      if (l < L && e < 300) v = *reinterpret_cast<const float4*>(xb + l * 300 + e);
      unsigned int lo = (unsigned int)f2bf(v.x) | ((unsigned int)f2bf(v.y) << 16);
      unsigned int hi = (unsigned int)f2bf(v.z) | ((unsigned int)f2bf(v.w) << 16);
      *reinterpret_cast<uint2*>(&As[r][e4 * 4]) = make_uint2(lo, hi);
    }
    // stage B: k planes x 128 c x 32 e (already bf16, 16B copies)
    for (int idx = t; idx < k * 512; idx += 256) {
      int j = idx >> 9;
      int rem = idx & 511;
      int c = rem >> 2, e8 = rem & 3;
      const uint4 v = *reinterpret_cast<const uint4*>(
          wt + (size_t)(pstart + j) * 40960 + c * 320 + ec + e8 * 8);
      *reinterpret_cast<uint4*>(&Bs[j][c][e8 * 8]) = v;
    }
    __syncthreads();

    for (int j = 0; j < k; ++j) {
      bf16x8 af[4], bfr[4];
      #pragma unroll
      for (int mi = 0; mi < 4; ++mi)
        af[mi] = *reinterpret_cast<const bf16x8*>(&As[m0 + mi * 16 + lrow + j][quad * 8]);
      #pragma unroll
      for (int ni = 0; ni < 4; ++ni)
        bfr[ni] = *reinterpret_cast<const bf16x8*>(&Bs[j][n0 + ni * 16 + lrow][quad * 8]);
      #pragma unroll
      for (int mi = 0; mi < 4; ++mi)
        #pragma unroll
        for (int ni = 0; ni < 4; ++ni)
          acc[mi][ni] = __builtin_amdgcn_mfma_f32_16x16x32_bf16(
              af[mi], bfr[ni], acc[mi][ni], 0, 0, 0);
    }
  }

  // epilogue: bias+relu, cross-wave ssq, normalize, store bf16 [l][c]
  float bv[4];
  #pragma unroll
  for (int ni = 0; ni < 4; ++ni) bv[ni] = bias[n0 + ni * 16 + lrow];

  #pragma unroll
  for (int mi = 0; mi < 4; ++mi) {
    #pragma unroll
    for (int r = 0; r < 4; ++r) {
      float p = 0.f;
      #pragma unroll
      for (int ni = 0; ni < 4; ++ni) {
        float y = fmaxf(acc[mi][ni][r] + bv[ni], 0.f);
        p += y * y;
      }
      p += __shfl_xor(p, 1); p += __shfl_xor(p, 2);
      p += __shfl_xor(p, 4); p += __shfl_xor(p, 8);
      if (lrow == 0) atomicAdd(&ssq[m0 + mi * 16 + quad * 4 + r], p);
    }
  }
  __syncthreads();

  unsigned short* ob = outT + ((size_t)(g * 128 + b) * L) * 128;
  #pragma unroll
  for (int mi = 0; mi < 4; ++mi) {
    #pragma unroll
    for (int r = 0; r < 4; ++r) {
      int row = m0 + mi * 16 + quad * 4 + r;
      int l = l0 + row;
      if (l < L) {
        float inv = 1.0f / (sqrtf(ssq[row]) + 1e-13f);
        #pragma unroll
        for (int ni = 0; ni < 4; ++ni) {
          float y = fmaxf(acc[mi][ni][r] + bv[ni], 0.f);
          ob[l * 128 + n0 + ni * 16 + lrow] = f2bf(y * inv);
        }
      }
    }
  }
}

// Block (pair, b), 128 thr = 8 qt x 16 dt; thread tile 4q x 4d with d rows
// strided by 16 (dt + 16*di) so float4 LDS reads stay 2-way conflict-free.
__global__ __launch_bounds__(128) void pool_kernel(
    const unsigned short* __restrict__ qn, const unsigned short* __restrict__ dn,
    const float* __restrict__ qmask, const float* __restrict__ dmask,
    float* __restrict__ pkq) {
  const float MU[11] = {1.0f, 0.9f, 0.7f, 0.5f, 0.3f, 0.1f,
                        -0.1f, -0.3f, -0.5f, -0.7f, -0.9f};
  const float INV2S2[11] = {500000.0f, 50.0f, 50.0f, 50.0f, 50.0f, 50.0f,
                            50.0f, 50.0f, 50.0f, 50.0f, 50.0f};
  const int pair = blockIdx.x;
  const int b    = blockIdx.y;
  const int ig   = pair / 3;
  const int tg   = pair % 3;
  const unsigned short* qslab = qn + (size_t)(ig * 128 + b) * 30 * 128;   // [q][c]
  const unsigned short* dslab = dn + (size_t)(tg * 128 + b) * 256 * 128;  // [d][c]

  __shared__ float qs[32][132];
  __shared__ float ds[64][132];

  const int t  = threadIdx.x;
  const int dt = t & 15, qt = t >> 4;
  const int q0 = qt * 4;

  for (int idx = t; idx < 32 * 32; idx += 128) {
    int r = idx >> 5, c4 = idx & 31;
    float4 f = make_float4(0.f, 0.f, 0.f, 0.f);
    if (r < 30) {
      uint2 v = *reinterpret_cast<const uint2*>(qslab + r * 128 + c4 * 4);
      f = make_float4(bf2f((unsigned short)(v.x & 0xFFFF)),
                      bf2f((unsigned short)(v.x >> 16)),
                      bf2f((unsigned short)(v.y & 0xFFFF)),
                      bf2f((unsigned short)(v.y >> 16)));
    }
    *reinterpret_cast<float4*>(&qs[r][c4 * 4]) = f;
  }

  float qm[4];
  #pragma unroll
  for (int qi = 0; qi < 4; ++qi) {
    int q = q0 + qi;
    qm[qi] = (q < 30) ? qmask[b * 30 + q] : 0.0f;
  }

  float feat[4][11];
  #pragma unroll
  for (int qi = 0; qi < 4; ++qi)
    #pragma unroll
    for (int kk = 0; kk < 11; ++kk) feat[qi][kk] = 0.0f;

  for (int ch = 0; ch < 4; ++ch) {
    __syncthreads();
    for (int idx = t; idx < 64 * 32; idx += 128) {
      int r = idx >> 5, c4 = idx & 31;
      uint2 v = *reinterpret_cast<const uint2*>(dslab + (size_t)(ch * 64 + r) * 128 + c4 * 4);
      *reinterpret_cast<float4*>(&ds[r][c4 * 4]) =
          make_float4(bf2f((unsigned short)(v.x & 0xFFFF)),
                      bf2f((unsigned short)(v.x >> 16)),
                      bf2f((unsigned short)(v.y & 0xFFFF)),
                      bf2f((unsigned short)(v.y >> 16)));
    }
    __syncthreads();

    float accq[4][4] = {};
    for (int c4 = 0; c4 < 32; ++c4) {
      float4 qv[4], dv[4];
      #pragma unroll
      for (int qi = 0; qi < 4; ++qi)
        qv[qi] = *reinterpret_cast<const float4*>(&qs[q0 + qi][c4 * 4]);
      #pragma unroll
      for (int di = 0; di < 4; ++di)
        dv[di] = *reinterpret_cast<const float4*>(&ds[dt + di * 16][c4 * 4]);
      #pragma unroll
      for (int qi = 0; qi < 4; ++qi)
        #pragma unroll
        for (int di = 0; di < 4; ++di)
          accq[qi][di] += qv[qi].x * dv[di].x + qv[qi].y * dv[di].y +
                          qv[qi].z * dv[di].z + qv[qi].w * dv[di].w;
    }

    float dm[4];
    #pragma unroll
    for (int di = 0; di < 4; ++di) dm[di] = dmask[b * 256 + ch * 64 + dt + di * 16];

    #pragma unroll
    for (int qi = 0; qi < 4; ++qi) {
      #pragma unroll
      for (int di = 0; di < 4; ++di) {
        float m  = qm[qi] * dm[di];
        float cm = accq[qi][di] * m;
        #pragma unroll
        for (int kk = 0; kk < 11; ++kk) {
          float d2 = cm - MU[kk];
          feat[qi][kk] += __expf(-d2 * d2 * INV2S2[kk]) * m;
        }
      }
    }
  }

  #pragma unroll
  for (int qi = 0; qi < 4; ++qi) {
    #pragma unroll
    for (int kk = 0; kk < 11; ++kk) {
      float v = feat[qi][kk];
      v += __shfl_xor(v, 1);
      v += __shfl_xor(v, 2);
      v += __shfl_xor(v, 4);
      v += __shfl_xor(v, 8);
      feat[qi][kk] = v;
    }
  }
  if (dt == 0) {
    #pragma unroll
    for (int qi = 0; qi < 4; ++qi) {
      int q = q0 + qi;
      if (q < 30) {
        float* p = pkq + ((size_t)(pair * 128 + b) * 30 + q) * 11;
        #pragma unroll
        for (int kk = 0; kk < 11; ++kk) p[kk] = feat[qi][kk];
      }
    }
  }
}

__global__ __launch_bounds__(128) void final_kernel(
    const float* __restrict__ pkq, const float* __restrict__ qmask,
    const float* __restrict__ dw, float* __restrict__ out) {
  const int b = blockIdx.x;
  const int t = threadIdx.x;
  float s = 0.0f;
  for (int idx = t; idx < 9 * 30 * 11; idx += 128) {
    int pair = idx / 330;
    int rem  = idx % 330;
    int q    = rem / 11;
    int kk   = rem % 11;
    float v = pkq[((size_t)(pair * 128 + b) * 30 + q) * 11 + kk];
    s += __logf(fmaxf(v, 1e-10f)) * 0.01f * qmask[b * 30 + q] * dw[pair * 11 + kk];
  }
  s += __shfl_xor(s, 1);  s += __shfl_xor(s, 2);  s += __shfl_xor(s, 4);
  s += __shfl_xor(s, 8);  s += __shfl_xor(s, 16); s += __shfl_xor(s, 32);
  __shared__ float part[2];
  if ((t & 63) == 0) part[t >> 6] = s;
  __syncthreads();
  if (t == 0) out[b] = part[0] + part[1];
}

extern "C" void kernel_launch(void* const* d_in, const int* in_sizes, int n_in,
                              void* d_out, int out_size, void* d_ws, size_t ws_size,
                              hipStream_t stream) {
  const float* qemb  = (const float*)d_in[0];
  const float* demb  = (const float*)d_in[1];
  const float* qmask = (const float*)d_in[2];
  const float* dmask = (const float*)d_in[3];
  const float* w1 = (const float*)d_in[4];
  const float* b1 = (const float*)d_in[5];
  const float* w2 = (const float*)d_in[6];
  const float* b2 = (const float*)d_in[7];
  const float* w3 = (const float*)d_in[8];
  const float* b3 = (const float*)d_in[9];
  const float* dw = (const float*)d_in[10];

  unsigned short* wt = (unsigned short*)d_ws;        // 245760 bf16
  unsigned short* qn = wt + 245760;                  // 1474560 bf16
  unsigned short* dn = qn + 1474560;                 // 12582912 bf16
  float*          pkq = (float*)(dn + 12582912);     // 380160 f32

  prep_w<<<960, 256, 0, stream>>>(w1, w2, w3, wt);
  conv_mfma<<<dim3(1, 128, 3), 256, 0, stream>>>(qemb, 30, wt, b1, b2, b3, qn);
  conv_mfma<<<dim3(2, 128, 3), 256, 0, stream>>>(demb, 256, wt, b1, b2, b3, dn);
  pool_kernel<<<dim3(9, 128), 128, 0, stream>>>(qn, dn, qmask, dmask, pkq);
  final_kernel<<<128, 128, 0, stream>>>(pkq, qmask, dw, (float*)d_out);
}

// Round 3
// 223.298 us; speedup vs baseline: 2.8092x; 1.3380x over previous
//
#include <hip/hip_runtime.h>
#include <math.h>

// Conv-KNRM on MI355X. B=128, QLEN=30, DLEN=256, EMB=300 (pad 320), C=128.
//
// Pipeline:
//   prep_w      : w fp32 [C,E,k] -> wt bf16 [plane(g,j)][c][320] (e zero-pad)
//   conv_mfma   : bf16 MFMA conv + bias + relu + L2-norm -> bf16 [g][b][l][c]
//   pool_mfma   : LDS-free MFMA cos (A=doc rows, B=query rows, K=c=128),
//                 RBF x11 on C-frags, d-sum via C-rows + quad shfl reduce.
//                 One wave per (tg, b, dchunk64); partials to pkq4[4 chunks].
//   final_kernel: sum 4 chunks, log/clip/qmask/sum_q dot dense_w -> out[128]
//
// ws: wt bf16 245760 | qn bf16 1474560 | dn bf16 12582912 | pkq4 f32 1520640

typedef __bf16 bf16x8 __attribute__((ext_vector_type(8)));
typedef float f32x4 __attribute__((ext_vector_type(4)));

#if __has_builtin(__builtin_amdgcn_exp2f)
#define EXP2F(x) __builtin_amdgcn_exp2f(x)
#else
#define EXP2F(x) exp2f(x)
#endif

static __device__ __forceinline__ unsigned short f2bf(float f) {
  union { float f; unsigned int u; } v; v.f = f;
  unsigned int r = v.u + 0x7FFFu + ((v.u >> 16) & 1u);  // RNE
  return (unsigned short)(r >> 16);
}

__global__ __launch_bounds__(256) void prep_w(
    const float* __restrict__ w1, const float* __restrict__ w2,
    const float* __restrict__ w3, unsigned short* __restrict__ wt) {
  int idx = blockIdx.x * 256 + threadIdx.x;
  if (idx >= 245760) return;  // 6 planes * 128 c * 320 e
  int e = idx % 320;
  int c = (idx / 320) & 127;
  int p = idx / 40960;
  const float* w; int k, j;
  if (p == 0)      { w = w1; k = 1; j = 0; }
  else if (p <= 2) { w = w2; k = 2; j = p - 1; }
  else             { w = w3; k = 3; j = p - 3; }
  float v = (e < 300) ? w[(c * 300 + e) * k + j] : 0.0f;
  wt[idx] = f2bf(v);
}

// Block: 128 l x 128 c tile for one (gram, batch). 256 thr = 4 waves, each
// 64x64 via 4x4 MFMA 16x16x32 frags. KC=32 e-chunk; A staged with +2 shift
// rows so all j taps reuse one LDS image.
__global__ __launch_bounds__(256) void conv_mfma(
    const float* __restrict__ x, int L,
    const unsigned short* __restrict__ wt,
    const float* __restrict__ b1, const float* __restrict__ b2,
    const float* __restrict__ b3,
    unsigned short* __restrict__ outT) {
  const int g = blockIdx.z;
  const int k = g + 1;
  const int pstart = (g * (g + 1)) >> 1;
  const float* bias = (g == 0 ? b1 : (g == 1 ? b2 : b3));
  const int b  = blockIdx.y;
  const int l0 = blockIdx.x * 128;

  __shared__ unsigned short As[130][40];
  __shared__ unsigned short Bs[3][128][40];
  __shared__ float ssq[128];

  const int t = threadIdx.x;
  const int wv = t >> 6, lane = t & 63;
  const int wm = wv >> 1, wn = wv & 1;
  const int m0 = wm * 64, n0 = wn * 64;
  const int quad = lane >> 4, lrow = lane & 15;

  if (t < 128) ssq[t] = 0.0f;

  f32x4 acc[4][4];
  #pragma unroll
  for (int i = 0; i < 4; ++i)
    #pragma unroll
    for (int jj = 0; jj < 4; ++jj) acc[i][jj] = (f32x4){0.f, 0.f, 0.f, 0.f};

  const float* xb = x + (size_t)b * L * 300;

  for (int ec = 0; ec < 320; ec += 32) {
    __syncthreads();
    for (int idx = t; idx < 130 * 8; idx += 256) {
      int r = idx >> 3, e4 = idx & 7;
      int e = ec + e4 * 4;
      int l = l0 + r;
      float4 v = make_float4(0.f, 0.f, 0.f, 0.f);
      if (l < L && e < 300) v = *reinterpret_cast<const float4*>(xb + l * 300 + e);
      unsigned int lo = (unsigned int)f2bf(v.x) | ((unsigned int)f2bf(v.y) << 16);
      unsigned int hi = (unsigned int)f2bf(v.z) | ((unsigned int)f2bf(v.w) << 16);
      *reinterpret_cast<uint2*>(&As[r][e4 * 4]) = make_uint2(lo, hi);
    }
    for (int idx = t; idx < k * 512; idx += 256) {
      int j = idx >> 9;
      int rem = idx & 511;
      int c = rem >> 2, e8 = rem & 3;
      const uint4 v = *reinterpret_cast<const uint4*>(
          wt + (size_t)(pstart + j) * 40960 + c * 320 + ec + e8 * 8);
      *reinterpret_cast<uint4*>(&Bs[j][c][e8 * 8]) = v;
    }
    __syncthreads();

    for (int j = 0; j < k; ++j) {
      bf16x8 af[4], bfr[4];
      #pragma unroll
      for (int mi = 0; mi < 4; ++mi)
        af[mi] = *reinterpret_cast<const bf16x8*>(&As[m0 + mi * 16 + lrow + j][quad * 8]);
      #pragma unroll
      for (int ni = 0; ni < 4; ++ni)
        bfr[ni] = *reinterpret_cast<const bf16x8*>(&Bs[j][n0 + ni * 16 + lrow][quad * 8]);
      #pragma unroll
      for (int mi = 0; mi < 4; ++mi)
        #pragma unroll
        for (int ni = 0; ni < 4; ++ni)
          acc[mi][ni] = __builtin_amdgcn_mfma_f32_16x16x32_bf16(
              af[mi], bfr[ni], acc[mi][ni], 0, 0, 0);
    }
  }

  float bv[4];
  #pragma unroll
  for (int ni = 0; ni < 4; ++ni) bv[ni] = bias[n0 + ni * 16 + lrow];

  #pragma unroll
  for (int mi = 0; mi < 4; ++mi) {
    #pragma unroll
    for (int r = 0; r < 4; ++r) {
      float p = 0.f;
      #pragma unroll
      for (int ni = 0; ni < 4; ++ni) {
        float y = fmaxf(acc[mi][ni][r] + bv[ni], 0.f);
        p += y * y;
      }
      p += __shfl_xor(p, 1); p += __shfl_xor(p, 2);
      p += __shfl_xor(p, 4); p += __shfl_xor(p, 8);
      if (lrow == 0) atomicAdd(&ssq[m0 + mi * 16 + quad * 4 + r], p);
    }
  }
  __syncthreads();

  unsigned short* ob = outT + ((size_t)(g * 128 + b) * L) * 128;
  #pragma unroll
  for (int mi = 0; mi < 4; ++mi) {
    #pragma unroll
    for (int r = 0; r < 4; ++r) {
      int row = m0 + mi * 16 + quad * 4 + r;
      int l = l0 + row;
      if (l < L) {
        float inv = 1.0f / (sqrtf(ssq[row]) + 1e-13f);
        #pragma unroll
        for (int ni = 0; ni < 4; ++ni) {
          float y = fmaxf(acc[mi][ni][r] + bv[ni], 0.f);
          ob[l * 128 + n0 + ni * 16 + lrow] = f2bf(y * inv);
        }
      }
    }
  }
}

// One wave per (tg, b, dchunk of 64). A = doc rows (M=d, 4 m-tiles held in
// regs, reused across 3 igs), B = query rows (N=q, 2 n-tiles). K = c = 128.
// C row = d -> RBF features accumulate per-lane over (mi, quad, reg);
// reduce across quads with 2 shfl_xor; lanes 0-15 store per-chunk partials.
__global__ __launch_bounds__(64) void pool_mfma(
    const unsigned short* __restrict__ qn, const unsigned short* __restrict__ dn,
    const float* __restrict__ qmask, const float* __restrict__ dmask,
    float* __restrict__ pkq4) {
  const float MU[11] = {1.0f, 0.9f, 0.7f, 0.5f, 0.3f, 0.1f,
                        -0.1f, -0.3f, -0.5f, -0.7f, -0.9f};
  // -1/(2*sigma^2) * log2(e)
  const float NEGC[11] = {-721347.52f, -72.134752f, -72.134752f, -72.134752f,
                          -72.134752f, -72.134752f, -72.134752f, -72.134752f,
                          -72.134752f, -72.134752f, -72.134752f};
  const int tg    = blockIdx.x >> 2;
  const int chunk = blockIdx.x & 3;
  const int b     = blockIdx.y;
  const int lane  = threadIdx.x;
  const int quad  = lane >> 4, l15 = lane & 15;
  const int d0    = chunk * 64;

  const unsigned short* dslab = dn + (size_t)(tg * 128 + b) * 256 * 128;

  bf16x8 aD[4][4];  // [mi][kt]
  #pragma unroll
  for (int mi = 0; mi < 4; ++mi)
    #pragma unroll
    for (int kt = 0; kt < 4; ++kt)
      aD[mi][kt] = *reinterpret_cast<const bf16x8*>(
          dslab + (size_t)(d0 + mi * 16 + l15) * 128 + kt * 32 + quad * 8);

  float dmv[4][4];  // [mi][r]: d = d0 + mi*16 + quad*4 + r
  #pragma unroll
  for (int mi = 0; mi < 4; ++mi)
    #pragma unroll
    for (int r = 0; r < 4; ++r)
      dmv[mi][r] = dmask[b * 256 + d0 + mi * 16 + quad * 4 + r];

  float qmv[2];
  qmv[0] = qmask[b * 30 + l15];
  qmv[1] = (16 + l15 < 30) ? qmask[b * 30 + 16 + l15] : 0.0f;

  #pragma unroll 1
  for (int ig = 0; ig < 3; ++ig) {
    const unsigned short* qslab = qn + (size_t)(ig * 128 + b) * 30 * 128;

    bf16x8 bQ[2][4];  // [ni][kt]; rows >=30 read adjacent ws data, masked out
    #pragma unroll
    for (int ni = 0; ni < 2; ++ni)
      #pragma unroll
      for (int kt = 0; kt < 4; ++kt)
        bQ[ni][kt] = *reinterpret_cast<const bf16x8*>(
            qslab + (size_t)(ni * 16 + l15) * 128 + kt * 32 + quad * 8);

    f32x4 acc[4][2];
    #pragma unroll
    for (int mi = 0; mi < 4; ++mi)
      #pragma unroll
      for (int ni = 0; ni < 2; ++ni) acc[mi][ni] = (f32x4){0.f, 0.f, 0.f, 0.f};

    #pragma unroll
    for (int kt = 0; kt < 4; ++kt)
      #pragma unroll
      for (int mi = 0; mi < 4; ++mi)
        #pragma unroll
        for (int ni = 0; ni < 2; ++ni)
          acc[mi][ni] = __builtin_amdgcn_mfma_f32_16x16x32_bf16(
              aD[mi][kt], bQ[ni][kt], acc[mi][ni], 0, 0, 0);

    float feat[2][11];
    #pragma unroll
    for (int ni = 0; ni < 2; ++ni)
      #pragma unroll
      for (int kk = 0; kk < 11; ++kk) feat[ni][kk] = 0.0f;

    #pragma unroll
    for (int mi = 0; mi < 4; ++mi) {
      #pragma unroll
      for (int r = 0; r < 4; ++r) {
        #pragma unroll
        for (int ni = 0; ni < 2; ++ni) {
          float m  = qmv[ni] * dmv[mi][r];
          float cm = acc[mi][ni][r] * m;
          #pragma unroll
          for (int kk = 0; kk < 11; ++kk) {
            float d2 = cm - MU[kk];
            feat[ni][kk] += EXP2F(d2 * d2 * NEGC[kk]) * m;
          }
        }
      }
    }

    // reduce across the 4 quads (d sub-rows)
    #pragma unroll
    for (int ni = 0; ni < 2; ++ni)
      #pragma unroll
      for (int kk = 0; kk < 11; ++kk) {
        float v = feat[ni][kk];
        v += __shfl_xor(v, 16);
        v += __shfl_xor(v, 32);
        feat[ni][kk] = v;
      }

    if (quad == 0) {
      const int pair = ig * 3 + tg;
      #pragma unroll
      for (int ni = 0; ni < 2; ++ni) {
        int q = ni * 16 + l15;
        if (q < 30) {
          float* p = pkq4 +
              (((size_t)(chunk * 9 + pair) * 128 + b) * 30 + q) * 11;
          #pragma unroll
          for (int kk = 0; kk < 11; ++kk) p[kk] = feat[ni][kk];
        }
      }
    }
  }
}

__global__ __launch_bounds__(128) void final_kernel(
    const float* __restrict__ pkq4, const float* __restrict__ qmask,
    const float* __restrict__ dw, float* __restrict__ out) {
  const int CH = 9 * 128 * 30 * 11;  // 380160
  const int b = blockIdx.x;
  const int t = threadIdx.x;
  float s = 0.0f;
  for (int idx = t; idx < 9 * 30 * 11; idx += 128) {
    int pair = idx / 330;
    int rem  = idx % 330;
    int q    = rem / 11;
    int kk   = rem % 11;
    size_t base = (((size_t)pair * 128 + b) * 30 + q) * 11 + kk;
    float v = pkq4[base] + pkq4[base + CH] + pkq4[base + 2 * CH] +
              pkq4[base + 3 * CH];
    s += __logf(fmaxf(v, 1e-10f)) * 0.01f * qmask[b * 30 + q] * dw[pair * 11 + kk];
  }
  s += __shfl_xor(s, 1);  s += __shfl_xor(s, 2);  s += __shfl_xor(s, 4);
  s += __shfl_xor(s, 8);  s += __shfl_xor(s, 16); s += __shfl_xor(s, 32);
  __shared__ float part[2];
  if ((t & 63) == 0) part[t >> 6] = s;
  __syncthreads();
  if (t == 0) out[b] = part[0] + part[1];
}

extern "C" void kernel_launch(void* const* d_in, const int* in_sizes, int n_in,
                              void* d_out, int out_size, void* d_ws, size_t ws_size,
                              hipStream_t stream) {
  const float* qemb  = (const float*)d_in[0];
  const float* demb  = (const float*)d_in[1];
  const float* qmask = (const float*)d_in[2];
  const float* dmask = (const float*)d_in[3];
  const float* w1 = (const float*)d_in[4];
  const float* b1 = (const float*)d_in[5];
  const float* w2 = (const float*)d_in[6];
  const float* b2 = (const float*)d_in[7];
  const float* w3 = (const float*)d_in[8];
  const float* b3 = (const float*)d_in[9];
  const float* dw = (const float*)d_in[10];

  unsigned short* wt = (unsigned short*)d_ws;        // 245760 bf16
  unsigned short* qn = wt + 245760;                  // 1474560 bf16
  unsigned short* dn = qn + 1474560;                 // 12582912 bf16
  float*          pkq4 = (float*)(dn + 12582912);    // 1520640 f32

  prep_w<<<960, 256, 0, stream>>>(w1, w2, w3, wt);
  conv_mfma<<<dim3(1, 128, 3), 256, 0, stream>>>(qemb, 30, wt, b1, b2, b3, qn);
  conv_mfma<<<dim3(2, 128, 3), 256, 0, stream>>>(demb, 256, wt, b1, b2, b3, dn);
  pool_mfma<<<dim3(12, 128), 64, 0, stream>>>(qn, dn, qmask, dmask, pkq4);
  final_kernel<<<128, 128, 0, stream>>>(pkq4, qmask, dw, (float*)d_out);
}